// Round 5
// baseline (28.395 us; speedup 1.0000x reference)
//
#include <hip/hip_runtime.h>

#define C 32
#define H 192
#define W 192
#define HW (H*W)        // 36864
#define NPIX (HW*2)     // 73728
#define KK 7

// ---------------- K1 (unchanged from R4): z[hw][o*2+n] = sum_c cw[o,c]*x[c][hw][n] ----------------
__global__ __launch_bounds__(256) void k1_mix(
    const float* __restrict__ x, const float* __restrict__ cw, float* __restrict__ z)
{
    __shared__ float wl[256];
    const int b  = blockIdx.x;
    const int l  = (b & 7) * 72 + (b >> 3);      // bijective XCD swizzle (576%8==0)
    const int hwblk = l >> 2;
    const int ob    = (l & 3) * 8;
    const int tid   = threadIdx.x;

    wl[tid] = cw[(ob + (tid & 7)) * C + (tid >> 3)];   // wl[c*8+oo]
    __syncthreads();

    const int hw = hwblk * 256 + tid;
    const float2* x2 = reinterpret_cast<const float2*>(x);
    float2 xv[C];
#pragma unroll
    for (int c = 0; c < C; ++c) xv[c] = x2[(size_t)c * HW + hw];

    float acc[8][2];
#pragma unroll
    for (int oo = 0; oo < 8; ++oo) { acc[oo][0] = 0.f; acc[oo][1] = 0.f; }

#pragma unroll
    for (int c = 0; c < C; ++c) {
        const float4 wa = *reinterpret_cast<const float4*>(&wl[c * 8]);
        const float4 wb = *reinterpret_cast<const float4*>(&wl[c * 8 + 4]);
        const float wt[8] = { wa.x, wa.y, wa.z, wa.w, wb.x, wb.y, wb.z, wb.w };
#pragma unroll
        for (int oo = 0; oo < 8; ++oo) {
            acc[oo][0] += wt[oo] * xv[c].x;
            acc[oo][1] += wt[oo] * xv[c].y;
        }
    }

    float* zp = z + (size_t)hw * 64 + ob * 2;
#pragma unroll
    for (int q = 0; q < 4; ++q) {
        float4 r = make_float4(acc[2*q][0], acc[2*q][1], acc[2*q+1][0], acc[2*q+1][1]);
        *reinterpret_cast<float4*>(zp + 4 * q) = r;
    }
}

// ---------------- K2 v5 ----------------
// Block = 256 thr (4 waves); wave = 8 output px of row h, lane = o*2+n.
// Weights: wave-uniform -> scalar loads (readfirstlane wv). No weight LDS, no stage barrier.
// z: 14-col row windows, 4-deep static row pipeline, branch-free interior.
#define K2_BLOCKS 1152   // 192 rows x 6 wq

template<bool WEDGE>
__device__ __forceinline__ void load_row(const float* __restrict__ z, int yy, int w0,
                                         int lane, float* buf)
{
    if (!WEDGE) {
        const float* p = z + ((size_t)yy * W + (w0 - 3)) * 64 + lane;
#pragma unroll
        for (int k = 0; k < 14; ++k) buf[k] = p[k * 64];
    } else {
        const float* p = z + (size_t)yy * W * 64 + lane;
#pragma unroll
        for (int k = 0; k < 14; ++k) {
            const int cc  = w0 - 3 + k;                       // uniform
            const int ccl = cc < 0 ? 0 : (cc > W - 1 ? W - 1 : cc);
            const float v = p[ccl * 64];
            buf[k] = (cc == ccl) ? v : 0.f;
        }
    }
}

__device__ __forceinline__ void fma_row(const float* __restrict__ w1, int i, int h, int w0,
                                        const float* buf, float* acc)
{
    const float* wp = w1 + (size_t)i * KK * HW + (size_t)h * W + w0;   // uniform -> s_load
#pragma unroll
    for (int j = 0; j < KK; ++j) {
#pragma unroll
        for (int px = 0; px < 8; ++px)
            acc[px] += wp[j * HW + px] * buf[j + px];
    }
}

template<bool WEDGE, bool HEDGE>
__device__ __forceinline__ void k2_body(const float* __restrict__ z, const float* __restrict__ w1,
                                        int h, int w0, int lane, float* acc)
{
    float b0[14], b1[14], b2[14], b3[14];
    auto LR = [&](float* buf, int i) {
        const int yy = h + i - 3;
        if (HEDGE && ((unsigned)yy >= (unsigned)H)) {
#pragma unroll
            for (int k = 0; k < 14; ++k) buf[k] = 0.f;
        } else {
            load_row<WEDGE>(z, yy, w0, lane, buf);
        }
    };
    LR(b0, 0); LR(b1, 1); LR(b2, 2); LR(b3, 3);
    fma_row(w1, 0, h, w0, b0, acc); LR(b0, 4);
    fma_row(w1, 1, h, w0, b1, acc); LR(b1, 5);
    fma_row(w1, 2, h, w0, b2, acc); LR(b2, 6);
    fma_row(w1, 3, h, w0, b3, acc);
    fma_row(w1, 4, h, w0, b0, acc);
    fma_row(w1, 5, h, w0, b1, acc);
    fma_row(w1, 6, h, w0, b2, acc);
}

__global__ __launch_bounds__(256) void k2_conv(
    const float* __restrict__ z, const float* __restrict__ w1,
    const float* __restrict__ cb, float* __restrict__ out)
{
    __shared__ float tr[4][8 * 66];

    const int b  = blockIdx.x;
    const int l  = (b & 7) * (K2_BLOCKS / 8) + (b >> 3);  // XCD row-band swizzle
    const int h  = l / 6;
    const int wq = l % 6;
    const int wv   = __builtin_amdgcn_readfirstlane(threadIdx.x >> 6);  // SGPR -> uniform w0
    const int lane = threadIdx.x & 63;                    // o*2+n
    const int w0   = wq * 32 + wv * 8;

    float acc[8];
#pragma unroll
    for (int p = 0; p < 8; ++p) acc[p] = 0.f;

    const bool wedge = (w0 == 0) || (w0 == 184);
    const bool hedge = (h < 3) || (h > 188);
    if (!wedge && !hedge)      k2_body<false, false>(z, w1, h, w0, lane, acc);
    else if (!wedge && hedge)  k2_body<false, true >(z, w1, h, w0, lane, acc);
    else if (wedge && !hedge)  k2_body<true,  false>(z, w1, h, w0, lane, acc);
    else                       k2_body<true,  true >(z, w1, h, w0, lane, acc);

    // epilogue: bias + per-wave LDS transpose -> 16B stores
    const float bias = cb[lane >> 1];
    float* trw = &tr[wv][0];
#pragma unroll
    for (int p = 0; p < 8; ++p) trw[p * 66 + lane] = acc[p] + bias;
    __syncthreads();

    const int o = lane >> 1, half = lane & 1;
    float v8[8];
#pragma unroll
    for (int m = 0; m < 8; ++m) {
        const int f = half * 8 + m;
        v8[m] = trw[(f >> 1) * 66 + o * 2 + (f & 1)];
    }
    float* obase = out + (size_t)o * NPIX + ((size_t)h * W + w0) * 2 + half * 8;
    *reinterpret_cast<float4*>(obase)     = make_float4(v8[0], v8[1], v8[2], v8[3]);
    *reinterpret_cast<float4*>(obase + 4) = make_float4(v8[4], v8[5], v8[6], v8[7]);
}

extern "C" void kernel_launch(void* const* d_in, const int* in_sizes, int n_in,
                              void* d_out, int out_size, void* d_ws, size_t ws_size,
                              hipStream_t stream) {
    const float* x  = (const float*)d_in[0];   // (C,H,W,2)
    const float* w1 = (const float*)d_in[1];   // (1,1,49,H,W)
    const float* cw = (const float*)d_in[2];   // (C_out, C_in)
    const float* cb = (const float*)d_in[3];   // (C,)
    float* z   = (float*)d_ws;                 // (HW, 64) transposed mix
    float* out = (float*)d_out;                // (C,H,W,2)

    hipLaunchKernelGGL(k1_mix, dim3(576), dim3(256), 0, stream, x, cw, z);
    hipLaunchKernelGGL(k2_conv, dim3(K2_BLOCKS), dim3(256), 0, stream, z, w1, cb, out);
}